// Round 9
// baseline (105.748 us; speedup 1.0000x reference)
//
#include <hip/hip_runtime.h>
#include <stdint.h>

#define NPTS 8192
#define DIM  256
#define CAP  32768       // global edge capacity (expected ~1100)
#define LDSE 8192        // in-LDS edge capacity for the UF kernel
#define IBCAP 256        // per-block in-band candidate capacity
#define BAND 2.0e-3f     // > bound ~9.8e-4 on |sim_exact - sim_fp16h| (unit rows)

typedef _Float16 f16x8  __attribute__((ext_vector_type(8)));
typedef float    f32x16 __attribute__((ext_vector_type(16)));

// ws layout: [0..64)  ctr: ctr[0]=edge count
//            [64..)   edges (CAP u32)
//            [1M..)   Vh    (4 MB fp16)

// ---------------------------------------------------------------------------
// Convert V fp32 -> fp16 high half (RTNE); block 0 zeroes the counter.
// ---------------------------------------------------------------------------
__global__ __launch_bounds__(256) void convert_kernel(
        const float* __restrict__ V, _Float16* __restrict__ Vh,
        unsigned* __restrict__ ctr) {
    if (blockIdx.x == 0 && threadIdx.x == 0) { ctr[0] = 0u; ctr[1] = 0u; }
    size_t t = (size_t)blockIdx.x * 256 + threadIdx.x;   // 262144 threads
    const float4* src = reinterpret_cast<const float4*>(V) + t * 2;
    float4 v0 = src[0], v1 = src[1];
    f16x8 h;
    h[0] = (_Float16)v0.x; h[1] = (_Float16)v0.y;
    h[2] = (_Float16)v0.z; h[3] = (_Float16)v0.w;
    h[4] = (_Float16)v1.x; h[5] = (_Float16)v1.y;
    h[6] = (_Float16)v1.z; h[7] = (_Float16)v1.w;
    *reinterpret_cast<f16x8*>(Vh + t * 8) = h;
}

__global__ void init_count(unsigned* ctr) {
    if (threadIdx.x == 0) { ctr[0] = 0u; ctr[1] = 0u; }
}

// ---------------------------------------------------------------------------
__device__ __forceinline__ void gload_lds16(const void* g, void* l) {
    __builtin_amdgcn_global_load_lds(
        (const __attribute__((address_space(1))) void*)g,
        (__attribute__((address_space(3))) void*)l, 16, 0, 0);
}

// ---------------------------------------------------------------------------
// h-only MFMA edge kernel v4: v3 geometry + T4 counted-vmcnt 3-slice ring
// + T2 LDS XOR swizzle (both-sides: pre-swizzled global source, rule #21).
//
// Tile 256(i) x 128(j), 256 threads = 4 waves (2x2), wave tile 128x64
// (4x2 of 32x32), v_mfma_f32_32x32x16_f16, KC=32, 3-slice LDS ring
// (stage-ahead-2): LA[3][256x32] + LB[3][128x32] = 72 KB -> 2 blocks/CU.
//
// Swizzle (per 1 KB instance = 16 rows x 4 x 16B slots):
//   physical_slot = logical_slot ^ (row & 7)   [slot bits 2:0]
//   read:  half_addr = (row*32 + blk*8) ^ ((row&7)<<3)   (row&7 == l31&7)
//   stage: gload_lds writes lane L -> physical slot L; lane L fetches the
//          logical slot sl(L) = L ^ ((L>>2)&7) ^ ((L>>4)&1)  (exact inverse;
//          verified bijective).  4 lanes/row still read one contiguous 64 B
//          global chunk (sl bits 5:2 cover lane bits with blk permuted), so
//          global coalescing is preserved.
//   -> lanes 0..7 hit 8 distinct 16B slots per 128 B window: conflict-free
//      (v3's linear layout was a measured 4-way = 1.58x penalty, m136).
//
// Schedule (T4): prologue STAGE(s0),STAGE(s1);
//   iter it: [it<6: STAGE(s_{it+2})]; s_waitcnt vmcnt(12/6/0); s_barrier;
//            COMPUTE(buf it%3); s_barrier.
// Counted vmcnt keeps 2 future slices' loads in flight across barriers
// (slice loads age >= 1 full iteration before consumption -> L2/HBM latency
// hidden).  Buffer reuse safe: STAGE(it+2) writes buf[(it-1)%3], whose
// readers all passed the previous trailing barrier.
// C/D layout (m74/m101): col = lane&31, row = (reg&3)+8*(reg>>2)+4*(lane>>5);
// dual-operand same-k-map convention verified absmax=0 rounds 3/5/6/7/8.
// ---------------------------------------------------------------------------
__global__ __launch_bounds__(256, 2) void edge_mfma(
        const _Float16* __restrict__ Vh,
        const float* __restrict__ V,
        const float* __restrict__ thr_p,
        unsigned* __restrict__ ctr,
        unsigned* __restrict__ edges) {
    // triangular decode over (bi: 32 row-tiles of 256, bj: 128-col tiles).
    // row bi holds bj in [2bi, 64); offset(bi) = bi*(65-bi); total 1056.
    int t = blockIdx.x;
    int bi = (int)((65.0f - sqrtf(4225.0f - 4.0f * (float)t)) * 0.5f);
    if (bi > 31) bi = 31;
    while (bi > 0 && bi * (65 - bi) > t) --bi;
    while ((bi + 1) * (64 - bi) <= t) ++bi;
    int bj = 2 * bi + (t - bi * (65 - bi));

    __shared__ _Float16 LA[3][256 * 32];       // 3 x 16 KB
    __shared__ _Float16 LB[3][128 * 32];       // 3 x  8 KB
    __shared__ unsigned ibl[IBCAP];            // in-band candidate keys
    __shared__ unsigned ibn;

    const float thr = thr_p[0];
    const float hi = thr + BAND, lo = thr - BAND;
    const int tid  = threadIdx.x;
    const int lane = tid & 63;
    const int wid  = tid >> 6;
    const int wr = wid >> 1, wc = wid & 1;     // 2x2 wave grid
    const int i0 = bi * 256, j0 = bj * 128;

    if (tid == 0) ibn = 0u;

    f32x16 acc[4][2];
#pragma unroll
    for (int a = 0; a < 4; ++a)
#pragma unroll
        for (int b = 0; b < 2; ++b) acc[a][b] = 0.0f;

    const int l31 = lane & 31, g = lane >> 5;
    const int xl8 = (l31 & 7) << 3;            // read-side XOR (halves)
    // stage-side: logical slot fetched by this lane (inverse of slot XOR)
    const int sl   = (lane ^ ((lane >> 2) & 7) ^ ((lane >> 4) & 1)) & 63;
    const int lrow = sl >> 2;                  // logical row within instance
    const int lblk = sl & 3;                   // logical 16B block within row

    // ---- stage one KC=32 slice: A=16 + B=8 instances (1 KB each), 6/wave
    auto STAGE = [&](int buf, int kc) {
#pragma unroll
        for (int q = 0; q < 6; ++q) {
            const int qq = wid * 6 + q;        // 0..23
            if (qq < 16) {                     // A: 16 instances x 16 rows
                const int grow = i0 + qq * 16 + lrow;
                gload_lds16(Vh + ((size_t)grow * DIM + kc + lblk * 8),
                            &LA[buf][qq * 512]);
            } else {                           // B: 8 instances x 16 rows
                const int ins = qq - 16;
                const int grow = j0 + ins * 16 + lrow;
                gload_lds16(Vh + ((size_t)grow * DIM + kc + lblk * 8),
                            &LB[buf][ins * 512]);
            }
        }
    };

    // ---- compute one KC=32 slice from buf: 2 k-steps x 8 MFMA ----
    auto COMPUTE = [&](int buf) {
#pragma unroll
        for (int s = 0; s < 2; ++s) {
            const int xo = (2 * s + g) * 8;    // logical half-offset in row
            f16x8 af[4], bf[2];
#pragma unroll
            for (int a = 0; a < 4; ++a) {
                const int row = wr * 128 + a * 32 + l31;
                af[a] = *(const f16x8*)&LA[buf][(row * 32 + xo) ^ xl8];
            }
#pragma unroll
            for (int b = 0; b < 2; ++b) {
                const int row = wc * 64 + b * 32 + l31;
                bf[b] = *(const f16x8*)&LB[buf][(row * 32 + xo) ^ xl8];
            }
#pragma unroll
            for (int a = 0; a < 4; ++a)
#pragma unroll
                for (int b = 0; b < 2; ++b)
                    acc[a][b] = __builtin_amdgcn_mfma_f32_32x32x16_f16(
                        af[a], bf[b], acc[a][b], 0, 0, 0);
        }
    };

    // ---- T4 ring: stage-ahead-2, counted vmcnt, raw barriers ----
    STAGE(0, 0);
    STAGE(1, 32);
#pragma unroll
    for (int it = 0; it < 8; ++it) {
        if (it < 6) STAGE((it + 2) % 3, (it + 2) * 32);
        if (it < 6)      asm volatile("s_waitcnt vmcnt(12)" ::: "memory");
        else if (it == 6) asm volatile("s_waitcnt vmcnt(6)" ::: "memory");
        else              asm volatile("s_waitcnt vmcnt(0)" ::: "memory");
        __builtin_amdgcn_s_barrier();
        COMPUTE(it % 3);
        __builtin_amdgcn_s_barrier();
    }

    // ---- epilogue pass 1: classify; sure edges emit, in-band defer ----
#pragma unroll
    for (int a = 0; a < 4; ++a)
#pragma unroll
        for (int b = 0; b < 2; ++b)
#pragma unroll
            for (int reg = 0; reg < 16; ++reg) {
                float sim = acc[a][b][reg];
                int rr = (reg & 3) + 8 * (reg >> 2) + 4 * g;
                int i = i0 + wr * 128 + a * 32 + rr;
                int j = j0 + wc * 64 + b * 32 + l31;
                if (j > i && sim >= lo) {
                    unsigned key = ((unsigned)i << 13) | (unsigned)j;
                    if (sim >= hi) {
                        unsigned p = atomicAdd(&ctr[0], 1u);
                        if (p < CAP) edges[p] = key;
                    } else {
                        unsigned p = atomicAdd(&ibn, 1u);
                        if (p < IBCAP) ibl[p] = key;
                    }
                }
            }
    __syncthreads();

    // ---- epilogue pass 2: exact fp64 re-resolution (acc regs dead) ----
    unsigned nib = ibn; if (nib > IBCAP) nib = IBCAP;
    const double thrd = (double)thr;
    for (unsigned q = tid; q < nib; q += 256) {
        unsigned key = ibl[q];
        int i = (int)(key >> 13), j = (int)(key & 8191u);
        const float4* a4 = reinterpret_cast<const float4*>(V + (size_t)i * DIM);
        const float4* b4 = reinterpret_cast<const float4*>(V + (size_t)j * DIM);
        double s = 0.0;
#pragma unroll 4
        for (int k = 0; k < DIM / 4; ++k) {
            float4 x = a4[k], y = b4[k];
            s += (double)x.x * y.x + (double)x.y * y.y
               + (double)x.z * y.z + (double)x.w * y.w;
        }
        if (s >= thrd) {
            unsigned p = atomicAdd(&ctr[0], 1u);
            if (p < CAP) edges[p] = key;
        }
    }
}

// ---------------------------------------------------------------------------
// fp32 fallback (exact path, no band) if ws is too small for Vh.
// ---------------------------------------------------------------------------
__global__ __launch_bounds__(256) void edge_kernel(
        const float* __restrict__ V,
        const float* __restrict__ thr_p,
        unsigned*    __restrict__ ctr,
        unsigned*    __restrict__ edges) {
    const int bi = blockIdx.y, bj = blockIdx.x;
    if (bj < bi) return;

    __shared__ float As[128 * 32];
    __shared__ float Bs[128 * 32];

    const float thr = thr_p[0];
    const int tid = threadIdx.x;
    const int tx = tid & 15, ty = tid >> 4;
    const int i0 = bi * 128, j0 = bj * 128;

    float acc[8][8];
#pragma unroll
    for (int r = 0; r < 8; ++r)
#pragma unroll
        for (int c = 0; c < 8; ++c) acc[r][c] = 0.f;

    const int srow = tid >> 3, sq = tid & 7;

    for (int kc = 0; kc < DIM; kc += 32) {
#pragma unroll
        for (int p = 0; p < 4; ++p) {
            int row = srow + 32 * p;
            float4 va = *reinterpret_cast<const float4*>(
                &V[(size_t)(i0 + row) * DIM + kc + sq * 4]);
            float4 vb = *reinterpret_cast<const float4*>(
                &V[(size_t)(j0 + row) * DIM + kc + sq * 4]);
            int w = row * 32 + ((sq ^ ((row >> 3) & 7)) << 2);
            *reinterpret_cast<float4*>(&As[w]) = va;
            *reinterpret_cast<float4*>(&Bs[w]) = vb;
        }
        __syncthreads();
#pragma unroll
        for (int k4 = 0; k4 < 8; ++k4) {
            const float* pA = &As[(ty * 8) * 32 + ((k4 ^ (ty & 7)) << 2)];
            const float* pB = &Bs[(tx * 8) * 32 + ((k4 ^ (tx & 7)) << 2)];
            float4 a[8], b[8];
#pragma unroll
            for (int r = 0; r < 8; ++r)
                a[r] = *reinterpret_cast<const float4*>(&pA[r * 32]);
#pragma unroll
            for (int c = 0; c < 8; ++c)
                b[c] = *reinterpret_cast<const float4*>(&pB[c * 32]);
#pragma unroll
            for (int r = 0; r < 8; ++r)
#pragma unroll
                for (int c = 0; c < 8; ++c) {
                    acc[r][c] = fmaf(a[r].x, b[c].x, acc[r][c]);
                    acc[r][c] = fmaf(a[r].y, b[c].y, acc[r][c]);
                    acc[r][c] = fmaf(a[r].z, b[c].z, acc[r][c]);
                    acc[r][c] = fmaf(a[r].w, b[c].w, acc[r][c]);
                }
        }
        __syncthreads();
    }
#pragma unroll
    for (int r = 0; r < 8; ++r)
#pragma unroll
        for (int c = 0; c < 8; ++c) {
            int i = i0 + ty * 8 + r;
            int j = j0 + tx * 8 + c;
            if (j > i && acc[r][c] >= thr) {
                unsigned p = atomicAdd(&ctr[0], 1u);
                if (p < CAP) edges[p] = ((unsigned)i << 13) | (unsigned)j;
            }
        }
}

// ---------------------------------------------------------------------------
// UF kernel (one block, 1024 threads): parallel winner-rounds exact replay
// of the sequential merge, then parallel root write-out.
//
// Winner-rounds correctness: per round each live edge e computes its current
// roots (ri,rj) and atomicMin's its packed key (= sequential order index)
// into S[ri], S[rj].  e applies iff it holds both slots.  (a) Every live
// edge f<e is then root-disjoint from e; disjoint unions commute, so e's
// state restricted to its roots equals its sequential state -> par[rj]=ri
// is the exact sequential effect.  (b) Winner root-sets are pairwise
// disjoint (shared root => equal slot value => equal key; keys unique), so
// parallel application + root-preserving compression is race-free, and
// concurrent phase-B finds cannot produce a false win.  (c) The globally
// smallest live key always wins -> >=1 retire/round.
// Ping-pong slot arrays: phase B clears the OTHER array, so each round has
// exactly 2 barriers (the second fused into __syncthreads_count liveness).
// ---------------------------------------------------------------------------
__global__ __launch_bounds__(1024) void uf_kernel(
        const unsigned* __restrict__ ctr,
        const unsigned* __restrict__ edges,
        int* __restrict__ out) {
    __shared__ int      par[NPTS];        // 32 KB
    __shared__ unsigned slotA[NPTS];      // 32 KB
    __shared__ unsigned slotB[NPTS];      // 32 KB
    __shared__ unsigned sedge[LDSE];      // 32 KB

    const int tid = threadIdx.x;

    unsigned EC = ctr[0]; if (EC > LDSE) EC = LDSE;

    for (int t = tid; t < NPTS; t += 1024) {
        par[t] = t; slotA[t] = 0xFFFFFFFFu; slotB[t] = 0xFFFFFFFFu;
    }
    for (unsigned e = tid; e < EC; e += 1024) sedge[e] = edges[e];
    __syncthreads();

    volatile int* vpar = par;

    for (int round = 0;; ++round) {
        unsigned* S = (round & 1) ? slotB : slotA;
        unsigned* T = (round & 1) ? slotA : slotB;

        // Phase A: finds against round-start state + slot bids
        for (unsigned e = tid; e < EC; e += 1024) {
            unsigned key = sedge[e];
            if (key & 0x80000000u) continue;
            int ri = (int)(key >> 13), rj = (int)(key & 8191u);
            int p;
            while ((p = vpar[ri]) != ri) ri = p;
            while ((p = vpar[rj]) != rj) rj = p;
            atomicMin(&S[ri], key);
            atomicMin(&S[rj], key);
        }
        __syncthreads();

        // Phase B: winners apply; clear other slot array; track liveness
        int mylive = 0;
        for (unsigned e = tid; e < EC; e += 1024) {
            unsigned key = sedge[e];
            if (key & 0x80000000u) continue;
            int i = (int)(key >> 13), j = (int)(key & 8191u);
            int ri = i, rj = j, p;
            while ((p = vpar[ri]) != ri) ri = p;
            while ((p = vpar[rj]) != rj) rj = p;
            if (S[ri] == key && S[rj] == key) {
                if (ri != rj) { par[rj] = ri; par[i] = ri; par[j] = ri; }
                sedge[e] = key | 0x80000000u;
            } else {
                mylive = 1;
            }
        }
        for (int t = tid; t < NPTS; t += 1024) T[t] = 0xFFFFFFFFu;
        if (__syncthreads_count(mylive) == 0) break;
    }

    // ---- root write-out ----
    for (int t = tid; t < NPTS; t += 1024) {
        int r = t, p;
        while ((p = par[r]) != r) r = p;
        out[t] = r;
    }
}

extern "C" void kernel_launch(void* const* d_in, const int* in_sizes, int n_in,
                              void* d_out, int out_size, void* d_ws, size_t ws_size,
                              hipStream_t stream) {
    const float* V     = (const float*)d_in[0];
    const float* thr_p = (const float*)d_in[1];
    // d_in[2] (batch_size) provably does not affect the result.

    unsigned* ctr   = (unsigned*)d_ws;
    unsigned* edges = (unsigned*)((char*)d_ws + 64);
    int*      out   = (int*)d_out;

    const size_t vhOff = 1u << 20;
    const size_t vN    = (size_t)NPTS * DIM;
    const size_t need  = vhOff + vN * sizeof(_Float16) + 65536;

    if (ws_size >= need) {
        _Float16* Vh = (_Float16*)((char*)d_ws + vhOff);
        hipLaunchKernelGGL(convert_kernel, dim3(1024), dim3(256), 0, stream,
                           V, Vh, ctr);
        hipLaunchKernelGGL(edge_mfma, dim3(1056), dim3(256), 0, stream,
                           Vh, V, thr_p, ctr, edges);
    } else {
        hipLaunchKernelGGL(init_count, dim3(1), dim3(64), 0, stream, ctr);
        hipLaunchKernelGGL(edge_kernel, dim3(64, 64), dim3(256), 0, stream,
                           V, thr_p, ctr, edges);
    }
    hipLaunchKernelGGL(uf_kernel, dim3(1), dim3(1024), 0, stream,
                       ctr, edges, out);
}

// Round 10
// 100.421 us; speedup vs baseline: 1.0530x; 1.0530x over previous
//
#include <hip/hip_runtime.h>
#include <stdint.h>

#define NPTS 8192
#define DIM  256
#define CAP  32768       // global edge capacity (expected ~1100)
#define LDSE 8192        // in-LDS edge capacity for the UF kernel
#define IBCAP 256        // per-block in-band candidate capacity
#define BAND 2.0e-3f     // > bound ~9.8e-4 on |sim_exact - sim_fp16h| (unit rows)

typedef _Float16 f16x8  __attribute__((ext_vector_type(8)));
typedef float    f32x16 __attribute__((ext_vector_type(16)));

// ws layout: [0..64)  ctr: ctr[0]=edge count
//            [64..)   edges (CAP u32)
//            [1M..)   Vt (4 MB fp16, FRAGMENT-MAJOR tiled layout)
//
// Tiled layout: chunk(blk,s) = 1 KB = rows blk*32..blk*32+31, halves s*16..+15.
//   half index of (row, k):  ((row>>5)*16 + (k>>4))*512 + (row&31)*16 + (k&15)
// A wave's 32x32x16 MFMA operand fragment (row-block blk, k-group s) is ONE
// contiguous 1 KB block: lane (l31,g) reads 16 B at chunk + (l31*2+g)*16B.
// -> direct global->register fragment loads, fully coalesced, no LDS at all.

// ---------------------------------------------------------------------------
// Convert V fp32 -> fp16 tiled layout; block 0 zeroes the counters.
// Thread t handles row = t>>5, halves q*8..q*8+7 (q = t&31): reads 32 B
// coalesced; writes one 16 B chunk-fragment (scattered 16B, negligible).
// ---------------------------------------------------------------------------
__global__ __launch_bounds__(256) void convert_kernel(
        const float* __restrict__ V, _Float16* __restrict__ Vt,
        unsigned* __restrict__ ctr) {
    if (blockIdx.x == 0 && threadIdx.x == 0) { ctr[0] = 0u; ctr[1] = 0u; }
    size_t t = (size_t)blockIdx.x * 256 + threadIdx.x;   // 262144 threads
    int row = (int)(t >> 5), q = (int)(t & 31);          // halves k = q*8..+7
    const float4* src = reinterpret_cast<const float4*>(V) + t * 2;
    float4 v0 = src[0], v1 = src[1];
    f16x8 h;
    h[0] = (_Float16)v0.x; h[1] = (_Float16)v0.y;
    h[2] = (_Float16)v0.z; h[3] = (_Float16)v0.w;
    h[4] = (_Float16)v1.x; h[5] = (_Float16)v1.y;
    h[6] = (_Float16)v1.z; h[7] = (_Float16)v1.w;
    size_t dst = ((size_t)(row >> 5) * 16 + (unsigned)(q >> 1)) * 512
               + (size_t)(row & 31) * 16 + (size_t)(q & 1) * 8;
    *reinterpret_cast<f16x8*>(Vt + dst) = h;
}

__global__ void init_count(unsigned* ctr) {
    if (threadIdx.x == 0) { ctr[0] = 0u; ctr[1] = 0u; }
}

// ---------------------------------------------------------------------------
// h-only MFMA edge kernel v5: ZERO-LDS, zero-barrier pure dataflow.
// 128x128 tile / 4 waves (2x2), wave tile 64x64 (2x2 of 32x32),
// v_mfma_f32_32x32x16_f16.  Per k-step: 4 coalesced 1 KB fragment loads
// (global->reg, dwordx4) + 4 MFMAs, 1-step register prefetch, full unroll.
// No __syncthreads in the k-loop -> waves run free; 16 waves/CU
// (__launch_bounds__(256,4), ~110 VGPR) hide L1/L2 latency by TLP+ILP.
// Rationale (R7-R9 post-mortem): time tracked occupancy only; all staged
// variants were latency-bound at <=8 waves/CU with both pipes <15% busy.
// Classification: sim >= thr+BAND -> sure edge; |sim-thr| < BAND -> deferred
// to in-block LDS list, re-resolved exactly in fp64 after acc regs die.
// A/B use the identical (lane,elem)->k map (k = s*16 + g*8 + j) as rounds
// 3-9 (absmax=0) -> MFMA k-permutation invariance preserved.
// C/D layout (m74/m101): col = lane&31, row = (reg&3)+8*(reg>>2)+4*(lane>>5).
// ---------------------------------------------------------------------------
__global__ __launch_bounds__(256, 4) void edge_mfma(
        const _Float16* __restrict__ Vt,
        const float* __restrict__ V,
        const float* __restrict__ thr_p,
        unsigned* __restrict__ ctr,
        unsigned* __restrict__ edges) {
    // triangular decode (verified R3/R5/R6): 2080 blocks of 128x128
    int t = blockIdx.x;
    int bi = (int)(64.5f - sqrtf(64.5f * 64.5f - 2.0f * (float)t));
    while (bi * 64 - (bi * (bi - 1)) / 2 > t) --bi;
    while ((bi + 1) * 64 - ((bi + 1) * bi) / 2 <= t) ++bi;
    int bj = bi + (t - (bi * 64 - (bi * (bi - 1)) / 2));

    __shared__ unsigned ibl[IBCAP];            // in-band candidate keys
    __shared__ unsigned ibn;

    const float thr = thr_p[0];
    const float hi = thr + BAND, lo = thr - BAND;
    const int tid  = threadIdx.x;
    const int lane = tid & 63;
    const int wid  = tid >> 6;
    const int wr = wid >> 1, wc = wid & 1;     // 2x2 wave grid
    const int i0 = bi * 128, j0 = bj * 128;

    if (tid == 0) ibn = 0u;
    __syncthreads();                           // publish ibn=0 (once)

    const int l31 = lane & 31, g = lane >> 5;
    const int co = ((l31 << 1) | g) << 3;      // lane offset in chunk (halves)

    // fragment base pointers: chunk stride 512 halves, row-block stride 8192
    const _Float16* pA = Vt + (size_t)((i0 >> 5) + wr * 2) * 8192 + co;
    const _Float16* pB = Vt + (size_t)((j0 >> 5) + wc * 2) * 8192 + co;

    f32x16 acc[2][2];
#pragma unroll
    for (int a = 0; a < 2; ++a)
#pragma unroll
        for (int b = 0; b < 2; ++b) acc[a][b] = 0.0f;

    // ---- k-loop: 16 steps, 4 loads + 4 MFMAs each, 1-step prefetch ----
    f16x8 a0 = *(const f16x8*)(pA);
    f16x8 a1 = *(const f16x8*)(pA + 8192);
    f16x8 b0 = *(const f16x8*)(pB);
    f16x8 b1 = *(const f16x8*)(pB + 8192);
#pragma unroll
    for (int s = 0; s < 16; ++s) {
        f16x8 na0, na1, nb0, nb1;
        if (s < 15) {
            const int o = (s + 1) * 512;
            na0 = *(const f16x8*)(pA + o);
            na1 = *(const f16x8*)(pA + 8192 + o);
            nb0 = *(const f16x8*)(pB + o);
            nb1 = *(const f16x8*)(pB + 8192 + o);
        }
        acc[0][0] = __builtin_amdgcn_mfma_f32_32x32x16_f16(a0, b0, acc[0][0], 0, 0, 0);
        acc[0][1] = __builtin_amdgcn_mfma_f32_32x32x16_f16(a0, b1, acc[0][1], 0, 0, 0);
        acc[1][0] = __builtin_amdgcn_mfma_f32_32x32x16_f16(a1, b0, acc[1][0], 0, 0, 0);
        acc[1][1] = __builtin_amdgcn_mfma_f32_32x32x16_f16(a1, b1, acc[1][1], 0, 0, 0);
        if (s < 15) { a0 = na0; a1 = na1; b0 = nb0; b1 = nb1; }
    }

    // ---- epilogue pass 1: classify; sure edges emit, in-band defer ----
#pragma unroll
    for (int a = 0; a < 2; ++a)
#pragma unroll
        for (int b = 0; b < 2; ++b)
#pragma unroll
            for (int reg = 0; reg < 16; ++reg) {
                float sim = acc[a][b][reg];
                int rr = (reg & 3) + 8 * (reg >> 2) + 4 * g;
                int i = i0 + wr * 64 + a * 32 + rr;
                int j = j0 + wc * 64 + b * 32 + l31;
                if (j > i && sim >= lo) {
                    unsigned key = ((unsigned)i << 13) | (unsigned)j;
                    if (sim >= hi) {
                        unsigned p = atomicAdd(&ctr[0], 1u);
                        if (p < CAP) edges[p] = key;
                    } else {
                        unsigned p = atomicAdd(&ibn, 1u);
                        if (p < IBCAP) ibl[p] = key;
                    }
                }
            }
    __syncthreads();

    // ---- epilogue pass 2: exact fp64 re-resolution (acc regs dead) ----
    unsigned nib = ibn; if (nib > IBCAP) nib = IBCAP;
    const double thrd = (double)thr;
    for (unsigned q = tid; q < nib; q += 256) {
        unsigned key = ibl[q];
        int i = (int)(key >> 13), j = (int)(key & 8191u);
        const float4* a4 = reinterpret_cast<const float4*>(V + (size_t)i * DIM);
        const float4* b4 = reinterpret_cast<const float4*>(V + (size_t)j * DIM);
        double s = 0.0;
#pragma unroll 4
        for (int k = 0; k < DIM / 4; ++k) {
            float4 x = a4[k], y = b4[k];
            s += (double)x.x * y.x + (double)x.y * y.y
               + (double)x.z * y.z + (double)x.w * y.w;
        }
        if (s >= thrd) {
            unsigned p = atomicAdd(&ctr[0], 1u);
            if (p < CAP) edges[p] = key;
        }
    }
}

// ---------------------------------------------------------------------------
// fp32 fallback (exact path, no band) if ws is too small for Vt.
// ---------------------------------------------------------------------------
__global__ __launch_bounds__(256) void edge_kernel(
        const float* __restrict__ V,
        const float* __restrict__ thr_p,
        unsigned*    __restrict__ ctr,
        unsigned*    __restrict__ edges) {
    const int bi = blockIdx.y, bj = blockIdx.x;
    if (bj < bi) return;

    __shared__ float As[128 * 32];
    __shared__ float Bs[128 * 32];

    const float thr = thr_p[0];
    const int tid = threadIdx.x;
    const int tx = tid & 15, ty = tid >> 4;
    const int i0 = bi * 128, j0 = bj * 128;

    float acc[8][8];
#pragma unroll
    for (int r = 0; r < 8; ++r)
#pragma unroll
        for (int c = 0; c < 8; ++c) acc[r][c] = 0.f;

    const int srow = tid >> 3, sq = tid & 7;

    for (int kc = 0; kc < DIM; kc += 32) {
#pragma unroll
        for (int p = 0; p < 4; ++p) {
            int row = srow + 32 * p;
            float4 va = *reinterpret_cast<const float4*>(
                &V[(size_t)(i0 + row) * DIM + kc + sq * 4]);
            float4 vb = *reinterpret_cast<const float4*>(
                &V[(size_t)(j0 + row) * DIM + kc + sq * 4]);
            int w = row * 32 + ((sq ^ ((row >> 3) & 7)) << 2);
            *reinterpret_cast<float4*>(&As[w]) = va;
            *reinterpret_cast<float4*>(&Bs[w]) = vb;
        }
        __syncthreads();
#pragma unroll
        for (int k4 = 0; k4 < 8; ++k4) {
            const float* pA = &As[(ty * 8) * 32 + ((k4 ^ (ty & 7)) << 2)];
            const float* pB = &Bs[(tx * 8) * 32 + ((k4 ^ (tx & 7)) << 2)];
            float4 a[8], b[8];
#pragma unroll
            for (int r = 0; r < 8; ++r)
                a[r] = *reinterpret_cast<const float4*>(&pA[r * 32]);
#pragma unroll
            for (int c = 0; c < 8; ++c)
                b[c] = *reinterpret_cast<const float4*>(&pB[c * 32]);
#pragma unroll
            for (int r = 0; r < 8; ++r)
#pragma unroll
                for (int c = 0; c < 8; ++c) {
                    acc[r][c] = fmaf(a[r].x, b[c].x, acc[r][c]);
                    acc[r][c] = fmaf(a[r].y, b[c].y, acc[r][c]);
                    acc[r][c] = fmaf(a[r].z, b[c].z, acc[r][c]);
                    acc[r][c] = fmaf(a[r].w, b[c].w, acc[r][c]);
                }
        }
        __syncthreads();
    }
#pragma unroll
    for (int r = 0; r < 8; ++r)
#pragma unroll
        for (int c = 0; c < 8; ++c) {
            int i = i0 + ty * 8 + r;
            int j = j0 + tx * 8 + c;
            if (j > i && acc[r][c] >= thr) {
                unsigned p = atomicAdd(&ctr[0], 1u);
                if (p < CAP) edges[p] = ((unsigned)i << 13) | (unsigned)j;
            }
        }
}

// ---------------------------------------------------------------------------
// UF kernel (one block, 1024 threads): parallel winner-rounds exact replay
// of the sequential merge, then parallel root write-out.
//
// Winner-rounds correctness: per round each live edge e computes its current
// roots (ri,rj) and atomicMin's its packed key (= sequential order index)
// into S[ri], S[rj].  e applies iff it holds both slots.  (a) Every live
// edge f<e is then root-disjoint from e; disjoint unions commute, so e's
// state restricted to its roots equals its sequential state -> par[rj]=ri
// is the exact sequential effect.  (b) Winner root-sets are pairwise
// disjoint (shared root => equal slot value => equal key; keys unique), so
// parallel application + root-preserving compression is race-free, and
// concurrent phase-B finds cannot produce a false win.  (c) The globally
// smallest live key always wins -> >=1 retire/round.
// Ping-pong slot arrays: phase B clears the OTHER array, so each round has
// exactly 2 barriers (the second fused into __syncthreads_count liveness).
// ---------------------------------------------------------------------------
__global__ __launch_bounds__(1024) void uf_kernel(
        const unsigned* __restrict__ ctr,
        const unsigned* __restrict__ edges,
        int* __restrict__ out) {
    __shared__ int      par[NPTS];        // 32 KB
    __shared__ unsigned slotA[NPTS];      // 32 KB
    __shared__ unsigned slotB[NPTS];      // 32 KB
    __shared__ unsigned sedge[LDSE];      // 32 KB

    const int tid = threadIdx.x;

    unsigned EC = ctr[0]; if (EC > LDSE) EC = LDSE;

    for (int t = tid; t < NPTS; t += 1024) {
        par[t] = t; slotA[t] = 0xFFFFFFFFu; slotB[t] = 0xFFFFFFFFu;
    }
    for (unsigned e = tid; e < EC; e += 1024) sedge[e] = edges[e];
    __syncthreads();

    volatile int* vpar = par;

    for (int round = 0;; ++round) {
        unsigned* S = (round & 1) ? slotB : slotA;
        unsigned* T = (round & 1) ? slotA : slotB;

        // Phase A: finds against round-start state + slot bids
        for (unsigned e = tid; e < EC; e += 1024) {
            unsigned key = sedge[e];
            if (key & 0x80000000u) continue;
            int ri = (int)(key >> 13), rj = (int)(key & 8191u);
            int p;
            while ((p = vpar[ri]) != ri) ri = p;
            while ((p = vpar[rj]) != rj) rj = p;
            atomicMin(&S[ri], key);
            atomicMin(&S[rj], key);
        }
        __syncthreads();

        // Phase B: winners apply; clear other slot array; track liveness
        int mylive = 0;
        for (unsigned e = tid; e < EC; e += 1024) {
            unsigned key = sedge[e];
            if (key & 0x80000000u) continue;
            int i = (int)(key >> 13), j = (int)(key & 8191u);
            int ri = i, rj = j, p;
            while ((p = vpar[ri]) != ri) ri = p;
            while ((p = vpar[rj]) != rj) rj = p;
            if (S[ri] == key && S[rj] == key) {
                if (ri != rj) { par[rj] = ri; par[i] = ri; par[j] = ri; }
                sedge[e] = key | 0x80000000u;
            } else {
                mylive = 1;
            }
        }
        for (int t = tid; t < NPTS; t += 1024) T[t] = 0xFFFFFFFFu;
        if (__syncthreads_count(mylive) == 0) break;
    }

    // ---- root write-out ----
    for (int t = tid; t < NPTS; t += 1024) {
        int r = t, p;
        while ((p = par[r]) != r) r = p;
        out[t] = r;
    }
}

extern "C" void kernel_launch(void* const* d_in, const int* in_sizes, int n_in,
                              void* d_out, int out_size, void* d_ws, size_t ws_size,
                              hipStream_t stream) {
    const float* V     = (const float*)d_in[0];
    const float* thr_p = (const float*)d_in[1];
    // d_in[2] (batch_size) provably does not affect the result.

    unsigned* ctr   = (unsigned*)d_ws;
    unsigned* edges = (unsigned*)((char*)d_ws + 64);
    int*      out   = (int*)d_out;

    const size_t vtOff = 1u << 20;
    const size_t vN    = (size_t)NPTS * DIM;
    const size_t need  = vtOff + vN * sizeof(_Float16) + 65536;

    if (ws_size >= need) {
        _Float16* Vt = (_Float16*)((char*)d_ws + vtOff);
        hipLaunchKernelGGL(convert_kernel, dim3(1024), dim3(256), 0, stream,
                           V, Vt, ctr);
        hipLaunchKernelGGL(edge_mfma, dim3(2080), dim3(256), 0, stream,
                           Vt, V, thr_p, ctr, edges);
    } else {
        hipLaunchKernelGGL(init_count, dim3(1), dim3(64), 0, stream, ctr);
        hipLaunchKernelGGL(edge_kernel, dim3(64, 64), dim3(256), 0, stream,
                           V, thr_p, ctr, edges);
    }
    hipLaunchKernelGGL(uf_kernel, dim3(1), dim3(1024), 0, stream,
                       ctr, edges, out);
}

// Round 11
// 100.221 us; speedup vs baseline: 1.0551x; 1.0020x over previous
//
#include <hip/hip_runtime.h>
#include <stdint.h>

#define NPTS 8192
#define DIM  256
#define CAP  32768       // global edge capacity (expected ~1100)
#define LDSE 8192        // in-LDS edge capacity for the UF kernel
#define IBCAP 256        // per-block in-band candidate capacity
#define BAND 2.0e-3f     // > bound ~9.8e-4 on |sim_exact - sim_fp16h| (unit rows)

typedef _Float16 f16x8  __attribute__((ext_vector_type(8)));
typedef float    f32x16 __attribute__((ext_vector_type(16)));

// ws layout: [0..64)  ctr: ctr[0]=edge count
//            [64..)   edges (CAP u32)
//            [1M..)   Vt (4 MB fp16, FRAGMENT-MAJOR tiled layout)
//
// Tiled layout: chunk(blk,s) = 1 KB = rows blk*32..blk*32+31, halves s*16..+15.
//   half index of (row, k):  ((row>>5)*16 + (k>>4))*512 + (row&31)*16 + (k&15)
// A wave's 32x32x16 MFMA operand fragment (row-block blk, k-group s) is ONE
// contiguous 1 KB block: lane (l31,g) reads 16 B at chunk + (l31*2+g)*16B.
// -> direct global->register fragment loads, fully coalesced, no LDS at all.

// ---------------------------------------------------------------------------
// Convert V fp32 -> fp16 tiled layout; block 0 zeroes the counters.
// ---------------------------------------------------------------------------
__global__ __launch_bounds__(256) void convert_kernel(
        const float* __restrict__ V, _Float16* __restrict__ Vt,
        unsigned* __restrict__ ctr) {
    if (blockIdx.x == 0 && threadIdx.x == 0) { ctr[0] = 0u; ctr[1] = 0u; }
    size_t t = (size_t)blockIdx.x * 256 + threadIdx.x;   // 262144 threads
    int row = (int)(t >> 5), q = (int)(t & 31);          // halves k = q*8..+7
    const float4* src = reinterpret_cast<const float4*>(V) + t * 2;
    float4 v0 = src[0], v1 = src[1];
    f16x8 h;
    h[0] = (_Float16)v0.x; h[1] = (_Float16)v0.y;
    h[2] = (_Float16)v0.z; h[3] = (_Float16)v0.w;
    h[4] = (_Float16)v1.x; h[5] = (_Float16)v1.y;
    h[6] = (_Float16)v1.z; h[7] = (_Float16)v1.w;
    size_t dst = ((size_t)(row >> 5) * 16 + (unsigned)(q >> 1)) * 512
               + (size_t)(row & 31) * 16 + (size_t)(q & 1) * 8;
    *reinterpret_cast<f16x8*>(Vt + dst) = h;
}

__global__ void init_count(unsigned* ctr) {
    if (threadIdx.x == 0) { ctr[0] = 0u; ctr[1] = 0u; }
}

// ---------------------------------------------------------------------------
// h-only MFMA edge kernel v6: zero-LDS dataflow + DEPTH-2 register pipeline.
// 128x128 tile / 4 waves (2x2), wave tile 64x64 (2x2 of 32x32),
// v_mfma_f32_32x32x16_f16.  Period-3 rotation (u,v,w): at step s issue the
// 4 fragment loads for step s+2, consume group s -> 8 loads in flight per
// wave, cover ~= 2 steps x 32 cyc x ~4 waves/SIMD ~= 256 cyc ~= L2 latency.
// (R8/R9/R10 all pinned at 46-47us with depth-1-equivalent cover ~128 cyc:
// latency-bound, not BW/LDS/barrier-bound.)  Compiler emits the counted
// s_waitcnt vmcnt(8) for register loads automatically (T4, no barriers).
// Classification: sim >= thr+BAND -> sure edge; |sim-thr| < BAND -> deferred
// to in-block LDS list, re-resolved exactly in fp64 after acc regs die.
// A/B use the identical (lane,elem)->k map (k = s*16 + g*8 + j) as rounds
// 3-10 (absmax=0) -> MFMA k-permutation invariance preserved.
// C/D layout (m74/m101): col = lane&31, row = (reg&3)+8*(reg>>2)+4*(lane>>5).
// ---------------------------------------------------------------------------
#define LOADG(d0, d1, d2, d3, off)                                   \
    d0 = *(const f16x8*)(pA + (off));                                \
    d1 = *(const f16x8*)(pA + 8192 + (off));                         \
    d2 = *(const f16x8*)(pB + (off));                                \
    d3 = *(const f16x8*)(pB + 8192 + (off));

#define MFMAG(x0, x1, x2, x3)                                                    \
    acc00 = __builtin_amdgcn_mfma_f32_32x32x16_f16(x0, x2, acc00, 0, 0, 0);      \
    acc01 = __builtin_amdgcn_mfma_f32_32x32x16_f16(x0, x3, acc01, 0, 0, 0);      \
    acc10 = __builtin_amdgcn_mfma_f32_32x32x16_f16(x1, x2, acc10, 0, 0, 0);      \
    acc11 = __builtin_amdgcn_mfma_f32_32x32x16_f16(x1, x3, acc11, 0, 0, 0);

__global__ __launch_bounds__(256, 4) void edge_mfma(
        const _Float16* __restrict__ Vt,
        const float* __restrict__ V,
        const float* __restrict__ thr_p,
        unsigned* __restrict__ ctr,
        unsigned* __restrict__ edges) {
    // triangular decode (verified R3/R5/R6/R10): 2080 blocks of 128x128
    int t = blockIdx.x;
    int bi = (int)(64.5f - sqrtf(64.5f * 64.5f - 2.0f * (float)t));
    while (bi * 64 - (bi * (bi - 1)) / 2 > t) --bi;
    while ((bi + 1) * 64 - ((bi + 1) * bi) / 2 <= t) ++bi;
    int bj = bi + (t - (bi * 64 - (bi * (bi - 1)) / 2));

    __shared__ unsigned ibl[IBCAP];            // in-band candidate keys
    __shared__ unsigned ibn;

    const float thr = thr_p[0];
    const float hi = thr + BAND, lo = thr - BAND;
    const int tid  = threadIdx.x;
    const int lane = tid & 63;
    const int wid  = tid >> 6;
    const int wr = wid >> 1, wc = wid & 1;     // 2x2 wave grid
    const int i0 = bi * 128, j0 = bj * 128;

    if (tid == 0) ibn = 0u;
    __syncthreads();                           // publish ibn=0 (once)

    const int l31 = lane & 31, g = lane >> 5;
    const int co = ((l31 << 1) | g) << 3;      // lane offset in chunk (halves)

    // fragment base pointers: chunk stride 512 halves, row-block stride 8192
    const _Float16* pA = Vt + (size_t)((i0 >> 5) + wr * 2) * 8192 + co;
    const _Float16* pB = Vt + (size_t)((j0 >> 5) + wc * 2) * 8192 + co;

    f32x16 acc00 = 0.0f, acc01 = 0.0f, acc10 = 0.0f, acc11 = 0.0f;

    // ---- k-loop: 16 steps, depth-2 prefetch, period-3 group rotation ----
    f16x8 u0, u1, u2, u3, v0, v1, v2, v3, w0, w1, w2, w3;
    LOADG(u0, u1, u2, u3, 0)                   // step 0
    LOADG(v0, v1, v2, v3, 512)                 // step 1
    LOADG(w0, w1, w2, w3,  2 * 512) MFMAG(u0, u1, u2, u3)   // s0
    LOADG(u0, u1, u2, u3,  3 * 512) MFMAG(v0, v1, v2, v3)   // s1
    LOADG(v0, v1, v2, v3,  4 * 512) MFMAG(w0, w1, w2, w3)   // s2
    LOADG(w0, w1, w2, w3,  5 * 512) MFMAG(u0, u1, u2, u3)   // s3
    LOADG(u0, u1, u2, u3,  6 * 512) MFMAG(v0, v1, v2, v3)   // s4
    LOADG(v0, v1, v2, v3,  7 * 512) MFMAG(w0, w1, w2, w3)   // s5
    LOADG(w0, w1, w2, w3,  8 * 512) MFMAG(u0, u1, u2, u3)   // s6
    LOADG(u0, u1, u2, u3,  9 * 512) MFMAG(v0, v1, v2, v3)   // s7
    LOADG(v0, v1, v2, v3, 10 * 512) MFMAG(w0, w1, w2, w3)   // s8
    LOADG(w0, w1, w2, w3, 11 * 512) MFMAG(u0, u1, u2, u3)   // s9
    LOADG(u0, u1, u2, u3, 12 * 512) MFMAG(v0, v1, v2, v3)   // s10
    LOADG(v0, v1, v2, v3, 13 * 512) MFMAG(w0, w1, w2, w3)   // s11
    LOADG(w0, w1, w2, w3, 14 * 512) MFMAG(u0, u1, u2, u3)   // s12
    LOADG(u0, u1, u2, u3, 15 * 512) MFMAG(v0, v1, v2, v3)   // s13
    MFMAG(w0, w1, w2, w3)                                   // s14
    MFMAG(u0, u1, u2, u3)                                   // s15

    // ---- epilogue pass 1: classify; sure edges emit, in-band defer ----
    f32x16 accs[2][2] = {{acc00, acc01}, {acc10, acc11}};
#pragma unroll
    for (int a = 0; a < 2; ++a)
#pragma unroll
        for (int b = 0; b < 2; ++b)
#pragma unroll
            for (int reg = 0; reg < 16; ++reg) {
                float sim = accs[a][b][reg];
                int rr = (reg & 3) + 8 * (reg >> 2) + 4 * g;
                int i = i0 + wr * 64 + a * 32 + rr;
                int j = j0 + wc * 64 + b * 32 + l31;
                if (j > i && sim >= lo) {
                    unsigned key = ((unsigned)i << 13) | (unsigned)j;
                    if (sim >= hi) {
                        unsigned p = atomicAdd(&ctr[0], 1u);
                        if (p < CAP) edges[p] = key;
                    } else {
                        unsigned p = atomicAdd(&ibn, 1u);
                        if (p < IBCAP) ibl[p] = key;
                    }
                }
            }
    __syncthreads();

    // ---- epilogue pass 2: exact fp64 re-resolution (acc regs dead) ----
    unsigned nib = ibn; if (nib > IBCAP) nib = IBCAP;
    const double thrd = (double)thr;
    for (unsigned q = tid; q < nib; q += 256) {
        unsigned key = ibl[q];
        int i = (int)(key >> 13), j = (int)(key & 8191u);
        const float4* a4 = reinterpret_cast<const float4*>(V + (size_t)i * DIM);
        const float4* b4 = reinterpret_cast<const float4*>(V + (size_t)j * DIM);
        double s = 0.0;
#pragma unroll 4
        for (int k = 0; k < DIM / 4; ++k) {
            float4 x = a4[k], y = b4[k];
            s += (double)x.x * y.x + (double)x.y * y.y
               + (double)x.z * y.z + (double)x.w * y.w;
        }
        if (s >= thrd) {
            unsigned p = atomicAdd(&ctr[0], 1u);
            if (p < CAP) edges[p] = key;
        }
    }
}

// ---------------------------------------------------------------------------
// fp32 fallback (exact path, no band) if ws is too small for Vt.
// ---------------------------------------------------------------------------
__global__ __launch_bounds__(256) void edge_kernel(
        const float* __restrict__ V,
        const float* __restrict__ thr_p,
        unsigned*    __restrict__ ctr,
        unsigned*    __restrict__ edges) {
    const int bi = blockIdx.y, bj = blockIdx.x;
    if (bj < bi) return;

    __shared__ float As[128 * 32];
    __shared__ float Bs[128 * 32];

    const float thr = thr_p[0];
    const int tid = threadIdx.x;
    const int tx = tid & 15, ty = tid >> 4;
    const int i0 = bi * 128, j0 = bj * 128;

    float acc[8][8];
#pragma unroll
    for (int r = 0; r < 8; ++r)
#pragma unroll
        for (int c = 0; c < 8; ++c) acc[r][c] = 0.f;

    const int srow = tid >> 3, sq = tid & 7;

    for (int kc = 0; kc < DIM; kc += 32) {
#pragma unroll
        for (int p = 0; p < 4; ++p) {
            int row = srow + 32 * p;
            float4 va = *reinterpret_cast<const float4*>(
                &V[(size_t)(i0 + row) * DIM + kc + sq * 4]);
            float4 vb = *reinterpret_cast<const float4*>(
                &V[(size_t)(j0 + row) * DIM + kc + sq * 4]);
            int w = row * 32 + ((sq ^ ((row >> 3) & 7)) << 2);
            *reinterpret_cast<float4*>(&As[w]) = va;
            *reinterpret_cast<float4*>(&Bs[w]) = vb;
        }
        __syncthreads();
#pragma unroll
        for (int k4 = 0; k4 < 8; ++k4) {
            const float* pA = &As[(ty * 8) * 32 + ((k4 ^ (ty & 7)) << 2)];
            const float* pB = &Bs[(tx * 8) * 32 + ((k4 ^ (tx & 7)) << 2)];
            float4 a[8], b[8];
#pragma unroll
            for (int r = 0; r < 8; ++r)
                a[r] = *reinterpret_cast<const float4*>(&pA[r * 32]);
#pragma unroll
            for (int c = 0; c < 8; ++c)
                b[c] = *reinterpret_cast<const float4*>(&pB[c * 32]);
#pragma unroll
            for (int r = 0; r < 8; ++r)
#pragma unroll
                for (int c = 0; c < 8; ++c) {
                    acc[r][c] = fmaf(a[r].x, b[c].x, acc[r][c]);
                    acc[r][c] = fmaf(a[r].y, b[c].y, acc[r][c]);
                    acc[r][c] = fmaf(a[r].z, b[c].z, acc[r][c]);
                    acc[r][c] = fmaf(a[r].w, b[c].w, acc[r][c]);
                }
        }
        __syncthreads();
    }
#pragma unroll
    for (int r = 0; r < 8; ++r)
#pragma unroll
        for (int c = 0; c < 8; ++c) {
            int i = i0 + ty * 8 + r;
            int j = j0 + tx * 8 + c;
            if (j > i && acc[r][c] >= thr) {
                unsigned p = atomicAdd(&ctr[0], 1u);
                if (p < CAP) edges[p] = ((unsigned)i << 13) | (unsigned)j;
            }
        }
}

// ---------------------------------------------------------------------------
// UF kernel (one block, 1024 threads): parallel winner-rounds exact replay
// of the sequential merge, then parallel root write-out.
// (Correctness argument unchanged from R6; verified absmax=0 rounds 6-10.)
// ---------------------------------------------------------------------------
__global__ __launch_bounds__(1024) void uf_kernel(
        const unsigned* __restrict__ ctr,
        const unsigned* __restrict__ edges,
        int* __restrict__ out) {
    __shared__ int      par[NPTS];        // 32 KB
    __shared__ unsigned slotA[NPTS];      // 32 KB
    __shared__ unsigned slotB[NPTS];      // 32 KB
    __shared__ unsigned sedge[LDSE];      // 32 KB

    const int tid = threadIdx.x;

    unsigned EC = ctr[0]; if (EC > LDSE) EC = LDSE;

    for (int t = tid; t < NPTS; t += 1024) {
        par[t] = t; slotA[t] = 0xFFFFFFFFu; slotB[t] = 0xFFFFFFFFu;
    }
    for (unsigned e = tid; e < EC; e += 1024) sedge[e] = edges[e];
    __syncthreads();

    volatile int* vpar = par;

    for (int round = 0;; ++round) {
        unsigned* S = (round & 1) ? slotB : slotA;
        unsigned* T = (round & 1) ? slotA : slotB;

        // Phase A: finds against round-start state + slot bids
        for (unsigned e = tid; e < EC; e += 1024) {
            unsigned key = sedge[e];
            if (key & 0x80000000u) continue;
            int ri = (int)(key >> 13), rj = (int)(key & 8191u);
            int p;
            while ((p = vpar[ri]) != ri) ri = p;
            while ((p = vpar[rj]) != rj) rj = p;
            atomicMin(&S[ri], key);
            atomicMin(&S[rj], key);
        }
        __syncthreads();

        // Phase B: winners apply; clear other slot array; track liveness
        int mylive = 0;
        for (unsigned e = tid; e < EC; e += 1024) {
            unsigned key = sedge[e];
            if (key & 0x80000000u) continue;
            int i = (int)(key >> 13), j = (int)(key & 8191u);
            int ri = i, rj = j, p;
            while ((p = vpar[ri]) != ri) ri = p;
            while ((p = vpar[rj]) != rj) rj = p;
            if (S[ri] == key && S[rj] == key) {
                if (ri != rj) { par[rj] = ri; par[i] = ri; par[j] = ri; }
                sedge[e] = key | 0x80000000u;
            } else {
                mylive = 1;
            }
        }
        for (int t = tid; t < NPTS; t += 1024) T[t] = 0xFFFFFFFFu;
        if (__syncthreads_count(mylive) == 0) break;
    }

    // ---- root write-out ----
    for (int t = tid; t < NPTS; t += 1024) {
        int r = t, p;
        while ((p = par[r]) != r) r = p;
        out[t] = r;
    }
}

extern "C" void kernel_launch(void* const* d_in, const int* in_sizes, int n_in,
                              void* d_out, int out_size, void* d_ws, size_t ws_size,
                              hipStream_t stream) {
    const float* V     = (const float*)d_in[0];
    const float* thr_p = (const float*)d_in[1];
    // d_in[2] (batch_size) provably does not affect the result.

    unsigned* ctr   = (unsigned*)d_ws;
    unsigned* edges = (unsigned*)((char*)d_ws + 64);
    int*      out   = (int*)d_out;

    const size_t vtOff = 1u << 20;
    const size_t vN    = (size_t)NPTS * DIM;
    const size_t need  = vtOff + vN * sizeof(_Float16) + 65536;

    if (ws_size >= need) {
        _Float16* Vt = (_Float16*)((char*)d_ws + vtOff);
        hipLaunchKernelGGL(convert_kernel, dim3(1024), dim3(256), 0, stream,
                           V, Vt, ctr);
        hipLaunchKernelGGL(edge_mfma, dim3(2080), dim3(256), 0, stream,
                           Vt, V, thr_p, ctr, edges);
    } else {
        hipLaunchKernelGGL(init_count, dim3(1), dim3(64), 0, stream, ctr);
        hipLaunchKernelGGL(edge_kernel, dim3(64, 64), dim3(256), 0, stream,
                           V, thr_p, ctr, edges);
    }
    hipLaunchKernelGGL(uf_kernel, dim3(1), dim3(1024), 0, stream,
                       ctr, edges, out);
}